// Round 4
// baseline (165.606 us; speedup 1.0000x reference)
//
#include <hip/hip_runtime.h>

// mus = W2·tanh(W1·x + b1) + b2, logvars = 0; parents(n) = max(n-8,0)..n-1 (node 0: itself).
//
// Round-4 = round-3 with the __fp16/_Float16 vector type mismatch fixed.
// Design: lane = node (perfect R/W coalescing, weights read once per thread):
//  - W1 held as packed f16 pairs -> 64 VGPRs (f32 version overflowed to AGPR
//    spills in round 1 at VGPR_Count=128)
//  - layer1 via v_dot2_f32_f16 (f16 multiply, f32 accumulate, acc seeded w/ b1)
//  - parent gather = 8 ds_bpermute of the lane's own gt value; window
//    max(n-8,0)+p matches parent_idx packing (pad slots hit zeroed W1 cols)
//  - clamp via v_med3_f32, tanh via Pade(5,4) rational (round-1 numerics,
//    absmax 0.0078 vs threshold 0.0273; f16 weights add ~1e-3)
//  - ~123 VGPRs -> __launch_bounds__(256,4) -> 4 waves/SIMD, grid 4096 waves

#define BATCH   131072
#define NODES   64
#define TPB     256
#define NBLOCKS 1024
#define NWAVES  (NBLOCKS * (TPB / 64))   // 4096
#define ROWS    (BATCH / NWAVES)         // 32

typedef float  v2f __attribute__((ext_vector_type(2)));
typedef __fp16 h2  __attribute__((ext_vector_type(2)));

__device__ __forceinline__ v2f tanh2(v2f x) {
    x.x = __builtin_amdgcn_fmed3f(x.x, -3.5f, 3.5f);
    x.y = __builtin_amdgcn_fmed3f(x.y, -3.5f, 3.5f);
    v2f x2  = x * x;
    v2f num = x2 * (x2 + 105.f) + 945.f;          // 945 + 105 x^2 + x^4
    v2f den = x2 * (x2 * 15.f + 420.f) + 945.f;   // 945 + 420 x^2 + 15 x^4
    v2f r;
    r.x = __builtin_amdgcn_rcpf(den.x);
    r.y = __builtin_amdgcn_rcpf(den.y);
    return x * num * r;
}

__global__ __launch_bounds__(TPB, 4)
void prior_kernel(const float* __restrict__ gt, const float* __restrict__ W1,
                  const float* __restrict__ b1, const float* __restrict__ W2,
                  const float* __restrict__ b2, float* __restrict__ out)
{
    const int lane = threadIdx.x & 63;              // node index
    const int wave = blockIdx.x * (TPB / 64) + (threadIdx.x >> 6);

    // ---- one-time: node weights into registers (f16 pairs for W1) ----
    h2 w1h[16][4];                                   // [h][p-pair]
    const float* w1p = W1 + lane * 128;
    #pragma unroll
    for (int i = 0; i < 32; ++i) {
        float4 f = ((const float4*)w1p)[i];
        const int h = i >> 1, j = (i & 1) * 2;
        w1h[h][j]     = __builtin_amdgcn_cvt_pkrtz(f.x, f.y);
        w1h[h][j + 1] = __builtin_amdgcn_cvt_pkrtz(f.z, f.w);
    }
    float b1r[16];
    #pragma unroll
    for (int i = 0; i < 4; ++i) {
        float4 f = ((const float4*)(b1 + lane * 16))[i];
        b1r[4 * i] = f.x; b1r[4 * i + 1] = f.y; b1r[4 * i + 2] = f.z; b1r[4 * i + 3] = f.w;
    }
    v2f w2r[8];
    #pragma unroll
    for (int i = 0; i < 4; ++i) {
        float4 f = ((const float4*)(W2 + lane * 16))[i];
        v2f a = { f.x, f.y }, c = { f.z, f.w };
        w2r[2 * i] = a; w2r[2 * i + 1] = c;
    }
    const float b2s = b2[lane];
    int base = lane - 8; if (base < 0) base = 0;     // parent window start

    // ---- stream batch rows ----
    int   b = wave;
    float g = gt[b * NODES + lane];
    for (int r = 0; r < ROWS; ++r) {
        const int bn = b + NWAVES;
        float gn = 0.f;
        if (r + 1 < ROWS) gn = gt[bn * NODES + lane];   // prefetch next row

        // gather 8 parent values from sibling lanes, pack to f16 pairs
        float xv[8];
        #pragma unroll
        for (int p = 0; p < 8; ++p) xv[p] = __shfl(g, base + p, 64);
        h2 xp[4];
        #pragma unroll
        for (int j = 0; j < 4; ++j) xp[j] = __builtin_amdgcn_cvt_pkrtz(xv[2 * j], xv[2 * j + 1]);

        v2f mu2 = { 0.f, 0.f };
        #pragma unroll
        for (int hh = 0; hh < 8; ++hh) {
            float a0 = b1r[2 * hh], a1 = b1r[2 * hh + 1];
            #pragma unroll
            for (int j = 0; j < 4; ++j) {
                a0 = __builtin_amdgcn_fdot2(xp[j], w1h[2 * hh][j],     a0, false);
                a1 = __builtin_amdgcn_fdot2(xp[j], w1h[2 * hh + 1][j], a1, false);
            }
            v2f hp = { a0, a1 };
            v2f t  = tanh2(hp);
            mu2 = __builtin_elementwise_fma(t, w2r[hh], mu2);
        }

        out[b * NODES + lane] = mu2.x + mu2.y + b2s;         // mus
        out[(size_t)BATCH * NODES + b * NODES + lane] = 0.f; // logvars
        g = gn; b = bn;
    }
}

extern "C" void kernel_launch(void* const* d_in, const int* in_sizes, int n_in,
                              void* d_out, int out_size, void* d_ws, size_t ws_size,
                              hipStream_t stream)
{
    const float* gt = (const float*)d_in[0];
    const float* W1 = (const float*)d_in[1];
    const float* b1 = (const float*)d_in[2];
    const float* W2 = (const float*)d_in[3];
    const float* b2 = (const float*)d_in[4];
    float* out = (float*)d_out;

    prior_kernel<<<NBLOCKS, TPB, 0, stream>>>(gt, W1, b1, W2, b2, out);
}

// Round 5
// 158.275 us; speedup vs baseline: 1.0463x; 1.0463x over previous
//
#include <hip/hip_runtime.h>

// mus = W2·tanh(W1·x + b1) + b2, logvars = 0; parents(n) = max(n-8,0)..n-1 (node 0: itself).
//
// Round-5: lane = node, f16 weights in VGPRs, two fixes vs round 4:
//  1. parent window loaded straight from global (2x dwordx4, dword-aligned,
//     windows overlap within the 256B row -> L1-served) -- replaces the
//     g-load + 8x ds_bpermute chain entirely. Zero LDS-pipe ops left.
//  2. __launch_bounds__(256,3) -> ~168-reg budget so the allocator keeps the
//     97 weight VGPRs in arch regs (rounds 1/4 AGPR-split at tight budgets,
//     costing ~2x VALU in v_accvgpr traffic). Persistent grid: 768 blocks =
//     3072 waves = exactly 3/SIMD, grid-stride row loop + branchless prefetch.
//
// Numerics identical to round 4 (passed, absmax 0.0078 vs threshold 0.0273):
// f16 weights via v_dot2_f32_f16 (f32 accumulate), Pade(5,4) tanh, med3 clamp.

#define BATCH   131072
#define NODES   64
#define TPB     256
#define NBLOCKS 768
#define NWAVES  (NBLOCKS * (TPB / 64))   // 3072 = 1024 SIMDs * 3 waves

typedef float  v2f __attribute__((ext_vector_type(2)));
typedef __fp16 h2  __attribute__((ext_vector_type(2)));
typedef float  f4u __attribute__((ext_vector_type(4), aligned(4)));  // dword-aligned float4

__device__ __forceinline__ v2f tanh2(v2f x) {
    x.x = __builtin_amdgcn_fmed3f(x.x, -3.5f, 3.5f);
    x.y = __builtin_amdgcn_fmed3f(x.y, -3.5f, 3.5f);
    v2f x2  = x * x;
    v2f num = x2 * (x2 + 105.f) + 945.f;          // 945 + 105 x^2 + x^4
    v2f den = x2 * (x2 * 15.f + 420.f) + 945.f;   // 945 + 420 x^2 + 15 x^4
    v2f r;
    r.x = __builtin_amdgcn_rcpf(den.x);
    r.y = __builtin_amdgcn_rcpf(den.y);
    return x * num * r;
}

__global__ __launch_bounds__(TPB, 3)
void prior_kernel(const float* __restrict__ gt, const float* __restrict__ W1,
                  const float* __restrict__ b1, const float* __restrict__ W2,
                  const float* __restrict__ b2, float* __restrict__ out)
{
    const int lane = threadIdx.x & 63;              // node index
    const int wave = blockIdx.x * (TPB / 64) + (threadIdx.x >> 6);

    // ---- one-time: node weights into registers (f16 pairs for W1) ----
    h2 w1h[16][4];                                   // [h][p-pair]
    const float* w1p = W1 + lane * 128;
    #pragma unroll
    for (int i = 0; i < 32; ++i) {
        float4 f = ((const float4*)w1p)[i];
        const int h = i >> 1, j = (i & 1) * 2;
        w1h[h][j]     = __builtin_amdgcn_cvt_pkrtz(f.x, f.y);
        w1h[h][j + 1] = __builtin_amdgcn_cvt_pkrtz(f.z, f.w);
    }
    float b1r[16];
    #pragma unroll
    for (int i = 0; i < 4; ++i) {
        float4 f = ((const float4*)(b1 + lane * 16))[i];
        b1r[4 * i] = f.x; b1r[4 * i + 1] = f.y; b1r[4 * i + 2] = f.z; b1r[4 * i + 3] = f.w;
    }
    v2f w2r[8];
    #pragma unroll
    for (int i = 0; i < 4; ++i) {
        float4 f = ((const float4*)(W2 + lane * 16))[i];
        v2f a = { f.x, f.y }, c = { f.z, f.w };
        w2r[2 * i] = a; w2r[2 * i + 1] = c;
    }
    const float b2s = b2[lane];

    // parent window: gt[b, base .. base+7], base = max(lane-8, 0).
    // For lane<8: slots p<lane hit nodes 0..lane-1 (= parent_idx packing),
    // slots p>=lane hit zeroed W1 columns -> any value is fine.
    int base = lane - 8; if (base < 0) base = 0;
    const float* xsrc = gt + base;

    // ---- stream batch rows (persistent grid, fully resident) ----
    int b = wave;
    f4u x0 = ((const f4u*)(xsrc + b * NODES))[0];
    f4u x1 = ((const f4u*)(xsrc + b * NODES))[1];
    while (b < BATCH) {
        const int bn  = b + NWAVES;
        const int bpf = (bn < BATCH) ? bn : b;       // branchless prefetch addr
        f4u n0 = ((const f4u*)(xsrc + bpf * NODES))[0];
        f4u n1 = ((const f4u*)(xsrc + bpf * NODES))[1];

        h2 xp[4];
        xp[0] = __builtin_amdgcn_cvt_pkrtz(x0.x, x0.y);
        xp[1] = __builtin_amdgcn_cvt_pkrtz(x0.z, x0.w);
        xp[2] = __builtin_amdgcn_cvt_pkrtz(x1.x, x1.y);
        xp[3] = __builtin_amdgcn_cvt_pkrtz(x1.z, x1.w);

        v2f mu2 = { 0.f, 0.f };
        #pragma unroll
        for (int hh = 0; hh < 8; ++hh) {
            float a0 = b1r[2 * hh], a1 = b1r[2 * hh + 1];
            #pragma unroll
            for (int j = 0; j < 4; ++j) {
                a0 = __builtin_amdgcn_fdot2(xp[j], w1h[2 * hh][j],     a0, false);
                a1 = __builtin_amdgcn_fdot2(xp[j], w1h[2 * hh + 1][j], a1, false);
            }
            v2f hp = { a0, a1 };
            v2f t  = tanh2(hp);
            mu2 = __builtin_elementwise_fma(t, w2r[hh], mu2);
        }

        out[b * NODES + lane] = mu2.x + mu2.y + b2s;            // mus
        out[(size_t)BATCH * NODES + b * NODES + lane] = 0.f;    // logvars
        x0 = n0; x1 = n1; b = bn;
    }
}

extern "C" void kernel_launch(void* const* d_in, const int* in_sizes, int n_in,
                              void* d_out, int out_size, void* d_ws, size_t ws_size,
                              hipStream_t stream)
{
    const float* gt = (const float*)d_in[0];
    const float* W1 = (const float*)d_in[1];
    const float* b1 = (const float*)d_in[2];
    const float* W2 = (const float*)d_in[3];
    const float* b2 = (const float*)d_in[4];
    float* out = (float*)d_out;

    prior_kernel<<<NBLOCKS, TPB, 0, stream>>>(gt, W1, b1, W2, b2, out);
}

// Round 6
// 155.550 us; speedup vs baseline: 1.0647x; 1.0175x over previous
//
#include <hip/hip_runtime.h>

// mus = W2·tanh(W1·x + b1) + b2, logvars = 0; parents(n) = max(n-8,0)..n-1 (node 0: itself).
//
// Round-6 = round-5 + anti-rematerialization pinning of the weight registers.
// Diagnosis: rounds 1/4/5 all show VGPR_Count < weight footprint with ideal
// FETCH/WRITE and ~55% VALUBusy -> LLVM RA remats the (invariant) weight loads
// into the row loop instead of keeping ~97 values live, thrashing L1 reloads
// every iteration. Fix: route each preloaded weight through an empty inline-asm
// with "+v" -> value is asm-defined, not rematerializable, must stay resident.
//
// Everything else identical to round 5 (passed, absmax 0.0078 vs thr 0.0273):
//  - lane = node; parent window = 2 dword-aligned dwordx4 global loads
//  - W1 as packed f16 pairs, layer1 via v_dot2_f32_f16 (f32 accumulate)
//  - Pade(5,4) tanh, med3 clamp
//  - persistent grid 768 blocks = 3072 waves = 3 waves/SIMD

#define BATCH   131072
#define NODES   64
#define TPB     256
#define NBLOCKS 768
#define NWAVES  (NBLOCKS * (TPB / 64))   // 3072 = 1024 SIMDs * 3 waves

typedef float  v2f __attribute__((ext_vector_type(2)));
typedef __fp16 h2  __attribute__((ext_vector_type(2)));
typedef float  f4u __attribute__((ext_vector_type(4), aligned(4)));  // dword-aligned float4

#define PIN(x) asm volatile("" : "+v"(x))

__device__ __forceinline__ v2f tanh2(v2f x) {
    x.x = __builtin_amdgcn_fmed3f(x.x, -3.5f, 3.5f);
    x.y = __builtin_amdgcn_fmed3f(x.y, -3.5f, 3.5f);
    v2f x2  = x * x;
    v2f num = x2 * (x2 + 105.f) + 945.f;          // 945 + 105 x^2 + x^4
    v2f den = x2 * (x2 * 15.f + 420.f) + 945.f;   // 945 + 420 x^2 + 15 x^4
    v2f r;
    r.x = __builtin_amdgcn_rcpf(den.x);
    r.y = __builtin_amdgcn_rcpf(den.y);
    return x * num * r;
}

__global__ __launch_bounds__(TPB, 3)
void prior_kernel(const float* __restrict__ gt, const float* __restrict__ W1,
                  const float* __restrict__ b1, const float* __restrict__ W2,
                  const float* __restrict__ b2, float* __restrict__ out)
{
    const int lane = threadIdx.x & 63;              // node index
    const int wave = blockIdx.x * (TPB / 64) + (threadIdx.x >> 6);

    // ---- one-time: node weights into registers (f16 pairs for W1) ----
    h2 w1h[16][4];                                   // [h][p-pair]
    const float* w1p = W1 + lane * 128;
    #pragma unroll
    for (int i = 0; i < 32; ++i) {
        float4 f = ((const float4*)w1p)[i];
        const int h = i >> 1, j = (i & 1) * 2;
        w1h[h][j]     = __builtin_amdgcn_cvt_pkrtz(f.x, f.y);
        w1h[h][j + 1] = __builtin_amdgcn_cvt_pkrtz(f.z, f.w);
    }
    float b1r[16];
    #pragma unroll
    for (int i = 0; i < 4; ++i) {
        float4 f = ((const float4*)(b1 + lane * 16))[i];
        b1r[4 * i] = f.x; b1r[4 * i + 1] = f.y; b1r[4 * i + 2] = f.z; b1r[4 * i + 3] = f.w;
    }
    v2f w2r[8];
    #pragma unroll
    for (int i = 0; i < 4; ++i) {
        float4 f = ((const float4*)(W2 + lane * 16))[i];
        v2f a = { f.x, f.y }, c = { f.z, f.w };
        w2r[2 * i] = a; w2r[2 * i + 1] = c;
    }
    float b2s = b2[lane];

    // pin every weight register: asm-defined values cannot be rematerialized,
    // so the RA must keep them live across the row loop instead of re-loading.
    #pragma unroll
    for (int h = 0; h < 16; ++h) {
        #pragma unroll
        for (int j = 0; j < 4; ++j) PIN(w1h[h][j]);
    }
    #pragma unroll
    for (int i = 0; i < 16; ++i) PIN(b1r[i]);
    #pragma unroll
    for (int i = 0; i < 8; ++i) PIN(w2r[i]);
    PIN(b2s);

    // parent window: gt[b, base .. base+7], base = max(lane-8, 0).
    // For lane<8: slots p<lane hit nodes 0..lane-1 (= parent_idx packing),
    // slots p>=lane hit zeroed W1 columns -> any value is fine.
    int base = lane - 8; if (base < 0) base = 0;
    const float* xsrc = gt + base;

    // ---- stream batch rows (persistent grid, fully resident) ----
    int b = wave;
    f4u x0 = ((const f4u*)(xsrc + b * NODES))[0];
    f4u x1 = ((const f4u*)(xsrc + b * NODES))[1];
    while (b < BATCH) {
        const int bn  = b + NWAVES;
        const int bpf = (bn < BATCH) ? bn : b;       // branchless prefetch addr
        f4u n0 = ((const f4u*)(xsrc + bpf * NODES))[0];
        f4u n1 = ((const f4u*)(xsrc + bpf * NODES))[1];

        h2 xp[4];
        xp[0] = __builtin_amdgcn_cvt_pkrtz(x0.x, x0.y);
        xp[1] = __builtin_amdgcn_cvt_pkrtz(x0.z, x0.w);
        xp[2] = __builtin_amdgcn_cvt_pkrtz(x1.x, x1.y);
        xp[3] = __builtin_amdgcn_cvt_pkrtz(x1.z, x1.w);

        v2f mu2 = { 0.f, 0.f };
        #pragma unroll
        for (int hh = 0; hh < 8; ++hh) {
            float a0 = b1r[2 * hh], a1 = b1r[2 * hh + 1];
            #pragma unroll
            for (int j = 0; j < 4; ++j) {
                a0 = __builtin_amdgcn_fdot2(xp[j], w1h[2 * hh][j],     a0, false);
                a1 = __builtin_amdgcn_fdot2(xp[j], w1h[2 * hh + 1][j], a1, false);
            }
            v2f hp = { a0, a1 };
            v2f t  = tanh2(hp);
            mu2 = __builtin_elementwise_fma(t, w2r[hh], mu2);
        }

        out[b * NODES + lane] = mu2.x + mu2.y + b2s;            // mus
        out[(size_t)BATCH * NODES + b * NODES + lane] = 0.f;    // logvars
        x0 = n0; x1 = n1; b = bn;
    }
}

extern "C" void kernel_launch(void* const* d_in, const int* in_sizes, int n_in,
                              void* d_out, int out_size, void* d_ws, size_t ws_size,
                              hipStream_t stream)
{
    const float* gt = (const float*)d_in[0];
    const float* W1 = (const float*)d_in[1];
    const float* b1 = (const float*)d_in[2];
    const float* W2 = (const float*)d_in[3];
    const float* b2 = (const float*)d_in[4];
    float* out = (float*)d_out;

    prior_kernel<<<NBLOCKS, TPB, 0, stream>>>(gt, W1, b1, W2, b2, out);
}